// Round 4
// baseline (198.395 us; speedup 1.0000x reference)
//
#include <hip/hip_runtime.h>
#include <math.h>

#define B 64
#define S 512
#define H 768
#define U 16
#define C 5
#define M (B*U)          // 1024 segments

typedef __attribute__((ext_vector_type(8))) short short8;
typedef __attribute__((ext_vector_type(4))) float floatx4;

__device__ inline unsigned short f2bf(float x) {          // round-to-nearest-even
    unsigned u = __float_as_uint(x);
    u += 0x7FFFu + ((u >> 16) & 1u);
    return (unsigned short)(u >> 16);
}
__device__ inline void acc4(float4& a, const float4& v) {
    a.x += v.x; a.y += v.y; a.z += v.z; a.w += v.w;
}

// ---------------------------------------------------------------------------
// Kernel 1 (fused prep):
//   blocks [0, M):         per-(b,u) segment mean -> bf16 means  (binary
//                          search over sorted seg row; 4-deep token unroll)
//   blocks [M, M+576):     Wh fp32 [K][N] -> Bt bf16 [N][K] (LDS transpose);
//                          first 27 of these also zero the logits buffer.
// ---------------------------------------------------------------------------
__global__ __launch_bounds__(192) void prep_kernel(
    const float* __restrict__ hidden, const int* __restrict__ seg,
    const float* __restrict__ Wh,
    unsigned short* __restrict__ means, unsigned short* __restrict__ Bt,
    float* __restrict__ logits)
{
    __shared__ float tile[32][33];
    const int t = threadIdx.x;

    if (blockIdx.x < M) {
        // ---- segment mean ----
        const int b = blockIdx.x >> 4;     // U = 16
        const int u = blockIdx.x & 15;
        const int* srow = seg + b * S;

        int lo = 0, hi = S;                // lower_bound(u)
        while (lo < hi) { int mid = (lo + hi) >> 1; if (srow[mid] < u) lo = mid + 1; else hi = mid; }
        const int start = lo;
        hi = S;                            // lower_bound(u+1)
        while (lo < hi) { int mid = (lo + hi) >> 1; if (srow[mid] < u + 1) lo = mid + 1; else hi = mid; }
        const int end = lo;

        const float4* h4 = (const float4*)(hidden + (size_t)b * S * H) + t;
        const int ldr = H / 4;

        float4 a0 = make_float4(0.f,0.f,0.f,0.f), a1 = a0, a2 = a0, a3 = a0;
        int s = start;
        #pragma unroll 2
        for (; s + 4 <= end; s += 4) {
            float4 v0 = h4[(size_t)(s + 0) * ldr];
            float4 v1 = h4[(size_t)(s + 1) * ldr];
            float4 v2 = h4[(size_t)(s + 2) * ldr];
            float4 v3 = h4[(size_t)(s + 3) * ldr];
            acc4(a0, v0); acc4(a1, v1); acc4(a2, v2); acc4(a3, v3);
        }
        for (; s < end; ++s) acc4(a0, h4[(size_t)s * ldr]);

        acc4(a0, a1); acc4(a2, a3); acc4(a0, a2);
        const float inv = 1.0f / fmaxf((float)(end - start), 1.0f);
        ushort4 o;
        o.x = f2bf(a0.x * inv); o.y = f2bf(a0.y * inv);
        o.z = f2bf(a0.z * inv); o.w = f2bf(a0.w * inv);
        ((ushort4*)(means + (size_t)(b * U + u) * H))[t] = o;
        return;
    }

    // ---- Wh transpose + bf16 convert (+ logits zero-init) ----
    const int tb = blockIdx.x - M;          // 0..575
    if (tb < 27) {                          // zero 1024*5 logits
        int i = tb * 192 + t;
        if (i < M * C) logits[i] = 0.f;
    }
    const int bn = tb % (H / 32);
    const int bk = tb / (H / 32);
    #pragma unroll
    for (int i = 0; i < 6; ++i) {
        int idx = t + 192 * i;
        if (idx < 1024) {
            int r = idx >> 5, c = idx & 31;
            tile[r][c] = Wh[(size_t)(bk * 32 + r) * H + bn * 32 + c];
        }
    }
    __syncthreads();
    #pragma unroll
    for (int i = 0; i < 6; ++i) {
        int idx = t + 192 * i;
        if (idx < 1024) {
            int r = idx >> 5, c = idx & 31;   // r = n within tile, c = k within tile
            Bt[(size_t)(bn * 32 + r) * H + bk * 32 + c] = f2bf(tile[c][r]);
        }
    }
}

// ---------------------------------------------------------------------------
// Kernel 2: selu(means @ Wh + bh) -> partial logits, fused.
// Wave owns a 16m x 32n tile (2 MFMAs/k-step, A-frag reused). Epilogue:
// y = selu(x); per-row partial logit sum over the wave's 32 n-columns via
// y*Wo[n][c], shfl_xor reduce across the 16 lanes of each row-quad, one
// atomicAdd per (row,class) per wave (24 adds/cell total). No hout buffer.
// ---------------------------------------------------------------------------
__global__ __launch_bounds__(256) void gemm1_fused_kernel(
    const unsigned short* __restrict__ means, const unsigned short* __restrict__ Bt,
    const float* __restrict__ bh, const float* __restrict__ Wo,
    float* __restrict__ logits)
{
    const int wid  = threadIdx.x >> 6;
    const int lane = threadIdx.x & 63;
    const int tile = blockIdx.x * 4 + wid;      // 0..1535
    const int tm = tile / (H / 32);             // 0..63
    const int tn = tile % (H / 32);             // 0..23
    const int m0 = tm * 16, n0 = tn * 32;

    const int quad = lane >> 4;
    const int l16  = lane & 15;

    const short8* ap  = (const short8*)(means + (size_t)(m0 + l16) * H);
    const short8* bp0 = (const short8*)(Bt    + (size_t)(n0 + l16) * H);
    const short8* bp1 = (const short8*)(Bt    + (size_t)(n0 + 16 + l16) * H);

    floatx4 acc0 = {0.f, 0.f, 0.f, 0.f}, acc1 = acc0;
    #pragma unroll 4
    for (int kk = 0; kk < H / 32; ++kk) {
        short8 a  = ap [4 * kk + quad];
        short8 b0 = bp0[4 * kk + quad];
        short8 b1 = bp1[4 * kk + quad];
        acc0 = __builtin_amdgcn_mfma_f32_16x16x32_bf16(a, b0, acc0, 0, 0, 0);
        acc1 = __builtin_amdgcn_mfma_f32_16x16x32_bf16(a, b1, acc1, 0, 0, 0);
    }

    const float SC = 1.0507009873554805f, AL = 1.6732632423543772f;
    const float bs0 = bh[n0 + l16], bs1 = bh[n0 + 16 + l16];
    float wo0[C], wo1[C];
    #pragma unroll
    for (int c = 0; c < C; ++c) {
        wo0[c] = Wo[(size_t)(n0 + l16) * C + c];
        wo1[c] = Wo[(size_t)(n0 + 16 + l16) * C + c];
    }

    #pragma unroll
    for (int r = 0; r < 4; ++r) {
        float x0 = acc0[r] + bs0;
        float x1 = acc1[r] + bs1;
        float y0 = x0 > 0.f ? SC * x0 : SC * AL * (expf(x0) - 1.f);
        float y1 = x1 > 0.f ? SC * x1 : SC * AL * (expf(x1) - 1.f);
        float p[C];
        #pragma unroll
        for (int c = 0; c < C; ++c) p[c] = y0 * wo0[c] + y1 * wo1[c];
        #pragma unroll
        for (int off = 1; off < 16; off <<= 1)
            #pragma unroll
            for (int c = 0; c < C; ++c) p[c] += __shfl_xor(p[c], off);
        if (l16 == 0) {
            float* dst = logits + (size_t)(m0 + quad * 4 + r) * C;
            #pragma unroll
            for (int c = 0; c < C; ++c) atomicAdd(dst + c, p[c]);
        }
    }
}

// ---------------------------------------------------------------------------
// Kernel 3: out = softmax(logits + bo) over C=5. One thread per row.
// ---------------------------------------------------------------------------
__global__ __launch_bounds__(256) void softmax_kernel(
    const float* __restrict__ logits, const float* __restrict__ bo,
    float* __restrict__ out)
{
    const int row = blockIdx.x * 256 + threadIdx.x;   // grid 4 -> 1024 rows
    float l[C], mx = -1e30f;
    #pragma unroll
    for (int c = 0; c < C; ++c) { l[c] = logits[(size_t)row * C + c] + bo[c]; mx = fmaxf(mx, l[c]); }
    float sum = 0.f;
    #pragma unroll
    for (int c = 0; c < C; ++c) { l[c] = expf(l[c] - mx); sum += l[c]; }
    const float rs = 1.0f / sum;
    #pragma unroll
    for (int c = 0; c < C; ++c) out[(size_t)row * C + c] = l[c] * rs;
}

// ---------------------------------------------------------------------------
extern "C" void kernel_launch(void* const* d_in, const int* in_sizes, int n_in,
                              void* d_out, int out_size, void* d_ws, size_t ws_size,
                              hipStream_t stream)
{
    const float* hidden = (const float*)d_in[0];
    const int*   seg    = (const int*)d_in[1];
    const float* Wh = (const float*)d_in[3];
    const float* bh = (const float*)d_in[4];
    const float* Wo = (const float*)d_in[5];
    const float* bo = (const float*)d_in[6];
    float* out = (float*)d_out;

    unsigned short* means  = (unsigned short*)d_ws;          // M*H bf16
    unsigned short* Bt     = means + (size_t)M * H;          // H*H bf16
    float*          logits = (float*)(Bt + (size_t)H * H);   // M*C fp32

    prep_kernel<<<M + (H / 32) * (H / 32), 192, 0, stream>>>(hidden, seg, Wh, means, Bt, logits);
    gemm1_fused_kernel<<<(M / 16) * (H / 32) / 4, 256, 0, stream>>>(means, Bt, bh, Wo, logits);
    softmax_kernel<<<M / 256, 256, 0, stream>>>(logits, bo, out);
}

// Round 5
// 184.035 us; speedup vs baseline: 1.0780x; 1.0780x over previous
//
#include <hip/hip_runtime.h>
#include <math.h>

#define B 64
#define S 512
#define H 768
#define U 16
#define C 5
#define M (B*U)          // 1024 segments

typedef __attribute__((ext_vector_type(8))) short short8;
typedef __attribute__((ext_vector_type(4))) float floatx4;

__device__ inline unsigned short f2bf(float x) {          // round-to-nearest-even
    unsigned u = __float_as_uint(x);
    u += 0x7FFFu + ((u >> 16) & 1u);
    return (unsigned short)(u >> 16);
}
__device__ inline void acc4(float4& a, const float4& v) {
    a.x += v.x; a.y += v.y; a.z += v.z; a.w += v.w;
}

// ---------------------------------------------------------------------------
// Kernel 1: per-(b,u) mean via binary search over the sorted seg row.
// One block per segment; 192 threads x float4. 12 waves/CU TLP saturates HBM.
// ---------------------------------------------------------------------------
__global__ __launch_bounds__(192) void seg_mean_kernel(
    const float* __restrict__ hidden, const int* __restrict__ seg,
    unsigned short* __restrict__ means)
{
    const int b = blockIdx.x >> 4;     // U = 16
    const int u = blockIdx.x & 15;
    const int* srow = seg + b * S;

    int lo = 0, hi = S;                // lower_bound(u)
    while (lo < hi) { int mid = (lo + hi) >> 1; if (srow[mid] < u) lo = mid + 1; else hi = mid; }
    const int start = lo;
    hi = S;                            // lower_bound(u+1)
    while (lo < hi) { int mid = (lo + hi) >> 1; if (srow[mid] < u + 1) lo = mid + 1; else hi = mid; }
    const int end = lo;

    const int t = threadIdx.x;         // 0..191
    const float4* h4 = (const float4*)(hidden + (size_t)b * S * H) + t;
    const int ldr = H / 4;

    float4 a0 = make_float4(0.f,0.f,0.f,0.f), a1 = a0, a2 = a0, a3 = a0;
    int s = start;
    #pragma unroll 2
    for (; s + 4 <= end; s += 4) {
        float4 v0 = h4[(size_t)(s + 0) * ldr];
        float4 v1 = h4[(size_t)(s + 1) * ldr];
        float4 v2 = h4[(size_t)(s + 2) * ldr];
        float4 v3 = h4[(size_t)(s + 3) * ldr];
        acc4(a0, v0); acc4(a1, v1); acc4(a2, v2); acc4(a3, v3);
    }
    for (; s < end; ++s) acc4(a0, h4[(size_t)s * ldr]);

    acc4(a0, a1); acc4(a2, a3); acc4(a0, a2);
    const float inv = 1.0f / fmaxf((float)(end - start), 1.0f);
    ushort4 o;
    o.x = f2bf(a0.x * inv); o.y = f2bf(a0.y * inv);
    o.z = f2bf(a0.z * inv); o.w = f2bf(a0.w * inv);
    ((ushort4*)(means + (size_t)(b * U + u) * H))[t] = o;
}

// ---------------------------------------------------------------------------
// Kernel 2: Wht_bf16[n][k] = bf16(Wh[k][n]) — LDS tiled transpose + convert.
// ---------------------------------------------------------------------------
__global__ __launch_bounds__(256) void wh_transpose_kernel(
    const float* __restrict__ Wh, unsigned short* __restrict__ Bt)
{
    __shared__ float tile[32][33];
    const int bn = blockIdx.x % (H / 32);
    const int bk = blockIdx.x / (H / 32);
    const int tx = threadIdx.x & 31;
    const int ty = threadIdx.x >> 5;        // 0..7
    #pragma unroll
    for (int i = 0; i < 4; ++i)
        tile[ty + 8 * i][tx] = Wh[(size_t)(bk * 32 + ty + 8 * i) * H + bn * 32 + tx];
    __syncthreads();
    #pragma unroll
    for (int i = 0; i < 4; ++i)
        Bt[(size_t)(bn * 32 + ty + 8 * i) * H + bk * 32 + tx] = f2bf(tile[tx][ty + 8 * i]);
}

// ---------------------------------------------------------------------------
// Kernel 3: hout = selu(means @ Wh + bh), bf16 MFMA 16x16x32, fp32 acc.
// Wave owns a 32m x 32n tile: 2 A-frags x 2 B-frags -> 4 MFMAs per k-step,
// 1:1 load:MFMA (vs 1.5:1 at 16x32), L2 traffic 74 MB. 768 waves = 192 blocks.
// A-frag: lane holds A[m=lane&15][k=quad*8+j]; B-frag: B[k=quad*8+j][n=lane&15]
// (Bt is [N][K]). C/D: col=lane&15, row=quad*4+r.
// ---------------------------------------------------------------------------
__global__ __launch_bounds__(256) void gemm1_mfma_kernel(
    const unsigned short* __restrict__ means, const unsigned short* __restrict__ Bt,
    const float* __restrict__ bh, float* __restrict__ hout)
{
    const int wid  = threadIdx.x >> 6;
    const int lane = threadIdx.x & 63;
    const int tile = blockIdx.x * 4 + wid;      // 0..767
    const int tm = tile / (H / 32);             // 0..31
    const int tn = tile % (H / 32);             // 0..23
    const int m0 = tm * 32, n0 = tn * 32;

    const int quad = lane >> 4;
    const int l16  = lane & 15;

    const short8* ap0 = (const short8*)(means + (size_t)(m0 + l16) * H);
    const short8* ap1 = (const short8*)(means + (size_t)(m0 + 16 + l16) * H);
    const short8* bp0 = (const short8*)(Bt    + (size_t)(n0 + l16) * H);
    const short8* bp1 = (const short8*)(Bt    + (size_t)(n0 + 16 + l16) * H);

    floatx4 acc00 = {0.f, 0.f, 0.f, 0.f}, acc01 = acc00, acc10 = acc00, acc11 = acc00;
    #pragma unroll 4
    for (int kk = 0; kk < H / 32; ++kk) {
        short8 a0 = ap0[4 * kk + quad];
        short8 a1 = ap1[4 * kk + quad];
        short8 b0 = bp0[4 * kk + quad];
        short8 b1 = bp1[4 * kk + quad];
        acc00 = __builtin_amdgcn_mfma_f32_16x16x32_bf16(a0, b0, acc00, 0, 0, 0);
        acc01 = __builtin_amdgcn_mfma_f32_16x16x32_bf16(a0, b1, acc01, 0, 0, 0);
        acc10 = __builtin_amdgcn_mfma_f32_16x16x32_bf16(a1, b0, acc10, 0, 0, 0);
        acc11 = __builtin_amdgcn_mfma_f32_16x16x32_bf16(a1, b1, acc11, 0, 0, 0);
    }

    const float SC = 1.0507009873554805f, AL = 1.6732632423543772f;
    const float bs0 = bh[n0 + l16], bs1 = bh[n0 + 16 + l16];
    #pragma unroll
    for (int r = 0; r < 4; ++r) {
        float* row0 = hout + (size_t)(m0 + quad * 4 + r) * H;
        float* row1 = hout + (size_t)(m0 + 16 + quad * 4 + r) * H;
        float x;
        x = acc00[r] + bs0; row0[n0 + l16]      = x > 0.f ? SC * x : SC * AL * (expf(x) - 1.f);
        x = acc01[r] + bs1; row0[n0 + 16 + l16] = x > 0.f ? SC * x : SC * AL * (expf(x) - 1.f);
        x = acc10[r] + bs0; row1[n0 + l16]      = x > 0.f ? SC * x : SC * AL * (expf(x) - 1.f);
        x = acc11[r] + bs1; row1[n0 + 16 + l16] = x > 0.f ? SC * x : SC * AL * (expf(x) - 1.f);
    }
}

// ---------------------------------------------------------------------------
// Kernel 4: logits = h @ Wo + bo, softmax over C=5. One wave per row.
// ---------------------------------------------------------------------------
__global__ __launch_bounds__(256) void head_kernel(
    const float* __restrict__ hbuf, const float* __restrict__ Wo,
    const float* __restrict__ bo, float* __restrict__ out)
{
    const int wave = threadIdx.x >> 6;
    const int lane = threadIdx.x & 63;
    const int row  = blockIdx.x * 4 + wave;

    float acc[C] = {};
    #pragma unroll
    for (int j = 0; j < H / 64; ++j) {
        int k = lane + 64 * j;
        float hv = hbuf[(size_t)row * H + k];
        #pragma unroll
        for (int cc = 0; cc < C; ++cc) acc[cc] += hv * Wo[k * C + cc];
    }
    #pragma unroll
    for (int off = 32; off >= 1; off >>= 1)
        #pragma unroll
        for (int cc = 0; cc < C; ++cc) acc[cc] += __shfl_down(acc[cc], off);

    if (lane == 0) {
        float l[C], mx = -1e30f;
        #pragma unroll
        for (int cc = 0; cc < C; ++cc) { l[cc] = acc[cc] + bo[cc]; mx = fmaxf(mx, l[cc]); }
        float sum = 0.f;
        #pragma unroll
        for (int cc = 0; cc < C; ++cc) { l[cc] = expf(l[cc] - mx); sum += l[cc]; }
        float r = 1.0f / sum;
        #pragma unroll
        for (int cc = 0; cc < C; ++cc) out[(size_t)row * C + cc] = l[cc] * r;
    }
}

// ---------------------------------------------------------------------------
extern "C" void kernel_launch(void* const* d_in, const int* in_sizes, int n_in,
                              void* d_out, int out_size, void* d_ws, size_t ws_size,
                              hipStream_t stream)
{
    const float* hidden = (const float*)d_in[0];
    const int*   seg    = (const int*)d_in[1];
    const float* Wh = (const float*)d_in[3];
    const float* bh = (const float*)d_in[4];
    const float* Wo = (const float*)d_in[5];
    const float* bo = (const float*)d_in[6];
    float* out = (float*)d_out;

    float*          hbuf  = (float*)d_ws;                            // M*H fp32
    unsigned short* means = (unsigned short*)(hbuf + (size_t)M * H); // M*H bf16
    unsigned short* Bt    = means + (size_t)M * H;                   // H*H bf16

    wh_transpose_kernel<<<(H / 32) * (H / 32), 256, 0, stream>>>(Wh, Bt);
    seg_mean_kernel<<<M, 192, 0, stream>>>(hidden, seg, means);
    gemm1_mfma_kernel<<<(M / 32) * (H / 32) / 4, 256, 0, stream>>>(means, Bt, bh, hbuf);
    head_kernel<<<M / 4, 256, 0, stream>>>(hbuf, Wo, bo, out);
}

// Round 6
// 183.003 us; speedup vs baseline: 1.0841x; 1.0056x over previous
//
#include <hip/hip_runtime.h>
#include <math.h>

#define B 64
#define S 512
#define H 768
#define U 16
#define C 5
#define M (B*U)          // 1024 segments

typedef __attribute__((ext_vector_type(8))) short short8;
typedef __attribute__((ext_vector_type(4))) float floatx4;

__device__ inline unsigned short f2bf(float x) {          // round-to-nearest-even
    unsigned u = __float_as_uint(x);
    u += 0x7FFFu + ((u >> 16) & 1u);
    return (unsigned short)(u >> 16);
}
__device__ inline float bf2f(unsigned short b) {
    return __uint_as_float((unsigned)b << 16);
}
__device__ inline void acc4(float4& a, const float4& v) {
    a.x += v.x; a.y += v.y; a.z += v.z; a.w += v.w;
}

// ---------------------------------------------------------------------------
// Kernel 1 (fused prep, independent work in one grid to save a launch gap):
//   blocks [0, M):      per-(b,u) segment mean -> bf16 means (binary search
//                       over the sorted seg row; 4-deep token unroll).
//   blocks [M, M+576):  Wh fp32 [K][N] -> Bt bf16 [N][K] via LDS transpose.
// ---------------------------------------------------------------------------
__global__ __launch_bounds__(192) void prep_kernel(
    const float* __restrict__ hidden, const int* __restrict__ seg,
    const float* __restrict__ Wh,
    unsigned short* __restrict__ means, unsigned short* __restrict__ Bt)
{
    __shared__ float tile[32][33];
    const int t = threadIdx.x;

    if (blockIdx.x < M) {
        // ---- segment mean ----
        const int b = blockIdx.x >> 4;     // U = 16
        const int u = blockIdx.x & 15;
        const int* srow = seg + b * S;

        int lo = 0, hi = S;                // lower_bound(u)
        while (lo < hi) { int mid = (lo + hi) >> 1; if (srow[mid] < u) lo = mid + 1; else hi = mid; }
        const int start = lo;
        hi = S;                            // lower_bound(u+1)
        while (lo < hi) { int mid = (lo + hi) >> 1; if (srow[mid] < u + 1) lo = mid + 1; else hi = mid; }
        const int end = lo;

        const float4* h4 = (const float4*)(hidden + (size_t)b * S * H) + t;
        const int ldr = H / 4;

        float4 a0 = make_float4(0.f,0.f,0.f,0.f), a1 = a0, a2 = a0, a3 = a0;
        int s = start;
        #pragma unroll 2
        for (; s + 4 <= end; s += 4) {
            float4 v0 = h4[(size_t)(s + 0) * ldr];
            float4 v1 = h4[(size_t)(s + 1) * ldr];
            float4 v2 = h4[(size_t)(s + 2) * ldr];
            float4 v3 = h4[(size_t)(s + 3) * ldr];
            acc4(a0, v0); acc4(a1, v1); acc4(a2, v2); acc4(a3, v3);
        }
        for (; s < end; ++s) acc4(a0, h4[(size_t)s * ldr]);

        acc4(a0, a1); acc4(a2, a3); acc4(a0, a2);
        const float inv = 1.0f / fmaxf((float)(end - start), 1.0f);
        ushort4 o;
        o.x = f2bf(a0.x * inv); o.y = f2bf(a0.y * inv);
        o.z = f2bf(a0.z * inv); o.w = f2bf(a0.w * inv);
        ((ushort4*)(means + (size_t)(b * U + u) * H))[t] = o;
        return;
    }

    // ---- Wh transpose + bf16 convert ----
    const int tb = blockIdx.x - M;          // 0..575
    const int bn = tb % (H / 32);
    const int bk = tb / (H / 32);
    #pragma unroll
    for (int i = 0; i < 6; ++i) {
        int idx = t + 192 * i;
        if (idx < 1024) {
            int r = idx >> 5, c = idx & 31;
            tile[r][c] = Wh[(size_t)(bk * 32 + r) * H + bn * 32 + c];
        }
    }
    __syncthreads();
    #pragma unroll
    for (int i = 0; i < 6; ++i) {
        int idx = t + 192 * i;
        if (idx < 1024) {
            int r = idx >> 5, c = idx & 31;   // r = n in tile, c = k in tile
            Bt[(size_t)(bn * 32 + r) * H + bk * 32 + c] = f2bf(tile[c][r]);
        }
    }
}

// ---------------------------------------------------------------------------
// Kernel 2: hbuf = bf16(selu(means @ Wh + bh)), bf16 MFMA 16x16x32, fp32 acc.
// Wave owns a 32m x 32n tile: 2 A-frags x 2 B-frags -> 4 MFMAs per k-step,
// 1:1 load:MFMA. 768 waves = 192 blocks. bf16 store halves hbuf traffic.
// ---------------------------------------------------------------------------
__global__ __launch_bounds__(256) void gemm1_mfma_kernel(
    const unsigned short* __restrict__ means, const unsigned short* __restrict__ Bt,
    const float* __restrict__ bh, unsigned short* __restrict__ hout)
{
    const int wid  = threadIdx.x >> 6;
    const int lane = threadIdx.x & 63;
    const int tile = blockIdx.x * 4 + wid;      // 0..767
    const int tm = tile / (H / 32);             // 0..31
    const int tn = tile % (H / 32);             // 0..23
    const int m0 = tm * 32, n0 = tn * 32;

    const int quad = lane >> 4;
    const int l16  = lane & 15;

    const short8* ap0 = (const short8*)(means + (size_t)(m0 + l16) * H);
    const short8* ap1 = (const short8*)(means + (size_t)(m0 + 16 + l16) * H);
    const short8* bp0 = (const short8*)(Bt    + (size_t)(n0 + l16) * H);
    const short8* bp1 = (const short8*)(Bt    + (size_t)(n0 + 16 + l16) * H);

    floatx4 acc00 = {0.f, 0.f, 0.f, 0.f}, acc01 = acc00, acc10 = acc00, acc11 = acc00;
    #pragma unroll 4
    for (int kk = 0; kk < H / 32; ++kk) {
        short8 a0 = ap0[4 * kk + quad];
        short8 a1 = ap1[4 * kk + quad];
        short8 b0 = bp0[4 * kk + quad];
        short8 b1 = bp1[4 * kk + quad];
        acc00 = __builtin_amdgcn_mfma_f32_16x16x32_bf16(a0, b0, acc00, 0, 0, 0);
        acc01 = __builtin_amdgcn_mfma_f32_16x16x32_bf16(a0, b1, acc01, 0, 0, 0);
        acc10 = __builtin_amdgcn_mfma_f32_16x16x32_bf16(a1, b0, acc10, 0, 0, 0);
        acc11 = __builtin_amdgcn_mfma_f32_16x16x32_bf16(a1, b1, acc11, 0, 0, 0);
    }

    const float SC = 1.0507009873554805f, AL = 1.6732632423543772f;
    const float bs0 = bh[n0 + l16], bs1 = bh[n0 + 16 + l16];
    #pragma unroll
    for (int r = 0; r < 4; ++r) {
        unsigned short* row0 = hout + (size_t)(m0 + quad * 4 + r) * H;
        unsigned short* row1 = hout + (size_t)(m0 + 16 + quad * 4 + r) * H;
        float x;
        x = acc00[r] + bs0; row0[n0 + l16]      = f2bf(x > 0.f ? SC * x : SC * AL * (expf(x) - 1.f));
        x = acc01[r] + bs1; row0[n0 + 16 + l16] = f2bf(x > 0.f ? SC * x : SC * AL * (expf(x) - 1.f));
        x = acc10[r] + bs0; row1[n0 + l16]      = f2bf(x > 0.f ? SC * x : SC * AL * (expf(x) - 1.f));
        x = acc11[r] + bs1; row1[n0 + 16 + l16] = f2bf(x > 0.f ? SC * x : SC * AL * (expf(x) - 1.f));
    }
}

// ---------------------------------------------------------------------------
// Kernel 3: logits = h @ Wo + bo, softmax over C=5. One wave per row;
// ushort2 (2 x bf16) loads per lane.
// ---------------------------------------------------------------------------
__global__ __launch_bounds__(256) void head_kernel(
    const unsigned short* __restrict__ hbuf, const float* __restrict__ Wo,
    const float* __restrict__ bo, float* __restrict__ out)
{
    const int wave = threadIdx.x >> 6;
    const int lane = threadIdx.x & 63;
    const int row  = blockIdx.x * 4 + wave;

    float acc[C] = {};
    #pragma unroll
    for (int j = 0; j < H / 128; ++j) {
        int k = 128 * j + 2 * lane;
        ushort2 hv = *(const ushort2*)(hbuf + (size_t)row * H + k);
        float h0 = bf2f(hv.x), h1 = bf2f(hv.y);
        #pragma unroll
        for (int cc = 0; cc < C; ++cc)
            acc[cc] += h0 * Wo[(size_t)k * C + cc] + h1 * Wo[(size_t)(k + 1) * C + cc];
    }
    #pragma unroll
    for (int off = 32; off >= 1; off >>= 1)
        #pragma unroll
        for (int cc = 0; cc < C; ++cc) acc[cc] += __shfl_down(acc[cc], off);

    if (lane == 0) {
        float l[C], mx = -1e30f;
        #pragma unroll
        for (int cc = 0; cc < C; ++cc) { l[cc] = acc[cc] + bo[cc]; mx = fmaxf(mx, l[cc]); }
        float sum = 0.f;
        #pragma unroll
        for (int cc = 0; cc < C; ++cc) { l[cc] = expf(l[cc] - mx); sum += l[cc]; }
        float r = 1.0f / sum;
        #pragma unroll
        for (int cc = 0; cc < C; ++cc) out[(size_t)row * C + cc] = l[cc] * r;
    }
}

// ---------------------------------------------------------------------------
extern "C" void kernel_launch(void* const* d_in, const int* in_sizes, int n_in,
                              void* d_out, int out_size, void* d_ws, size_t ws_size,
                              hipStream_t stream)
{
    const float* hidden = (const float*)d_in[0];
    const int*   seg    = (const int*)d_in[1];
    const float* Wh = (const float*)d_in[3];
    const float* bh = (const float*)d_in[4];
    const float* Wo = (const float*)d_in[5];
    const float* bo = (const float*)d_in[6];
    float* out = (float*)d_out;

    unsigned short* means = (unsigned short*)d_ws;           // M*H bf16
    unsigned short* Bt    = means + (size_t)M * H;           // H*H bf16
    unsigned short* hbuf  = Bt + (size_t)H * H;              // M*H bf16

    prep_kernel<<<M + (H / 32) * (H / 32), 192, 0, stream>>>(hidden, seg, Wh, means, Bt);
    gemm1_mfma_kernel<<<(M / 32) * (H / 32) / 4, 256, 0, stream>>>(means, Bt, bh, hbuf);
    head_kernel<<<M / 4, 256, 0, stream>>>(hbuf, Wo, bo, out);
}